// Round 11
// baseline (778.754 us; speedup 1.0000x reference)
//
#include <hip/hip_runtime.h>

constexpr int N    = 50000;
constexpr int E    = 800000;
constexpr int NG   = 64;
constexpr int ODIM = 10;
constexpr int OUTC = 128;
constexpr int GP_BLOCKS = 256;
constexpr int SCAN_B = (N + 255) / 256;   // 196
constexpr int CS1B   = 784;               // colsum stage-1 blocks
constexpr int NBS    = (N + 255) / 256;   // node-blocks per slice (196)
constexpr float SCALE    = 32768.0f;      // 2^15 for U = D^-1/2 Z (fp8 e4m3)
constexpr float INVSCALE = 1.0f / SCALE;

typedef float floatx2 __attribute__((ext_vector_type(2)));

// ---------- fp8 e4m3 helpers (r9-proven) ----------
__device__ __forceinline__ void unp4(unsigned int u, float* f) {
    floatx2 lo = __builtin_amdgcn_cvt_pk_f32_fp8(u, false);
    floatx2 hi = __builtin_amdgcn_cvt_pk_f32_fp8(u, true);
    f[0] = lo.x; f[1] = lo.y; f[2] = hi.x; f[3] = hi.y;
}
__device__ __forceinline__ unsigned int pk4(float a, float b, float c, float d) {
    int r = __builtin_amdgcn_cvt_pk_fp8_f32(a, b, 0, false);
    r = __builtin_amdgcn_cvt_pk_fp8_f32(c, d, r, true);
    return (unsigned int)r;
}

// Z layout is SLICE-MAJOR: slice q (graphs 8q..8q+7) is a contiguous N x 8B
// array: ZU2[q*N + i]. Per-slice working set = 400 KB -> L2-resident gathers.

// ---------- init ----------
__global__ void k_init0(int* degI, int* cnt, int* cntg, float* svec) {
    int i = blockIdx.x * 256 + threadIdx.x;
    if (i < N) { degI[i] = 1; cnt[i] = 0; }
    if (i < NG) cntg[i] = 0;
    if (i < 128) svec[i] = 0.f;
}

__global__ void k_edge_count(const int* __restrict__ ei, int* degI, int* cnt,
                             int* __restrict__ pos_e) {
    int e = blockIdx.x * 256 + threadIdx.x;
    if (e < E) {
        int s = ei[e];
        int d = ei[E + e];
        atomicAdd(&degI[d], 1);                  // in-degree at dst
        pos_e[e] = atomicAdd(&cnt[s], 1);        // out-degree + slot
    }
}

// scan1 + per-node scales fused
__global__ void k_scan1(const int* __restrict__ cnt, int* __restrict__ off, int* bsum,
                        const int* __restrict__ degI, float* wsq, float* sdeg) {
    __shared__ int buf[256];
    int tid = threadIdx.x;
    int i = blockIdx.x * 256 + tid;
    int v = (i < N) ? cnt[i] : 0;
    if (i < N) {
        float d = (float)degI[i];
        wsq[i]  = 1.0f / d;
        sdeg[i] = sqrtf(d);
    }
    buf[tid] = v;
    __syncthreads();
    for (int s = 1; s < 256; s <<= 1) {
        int add = (tid >= s) ? buf[tid - s] : 0;
        __syncthreads();
        buf[tid] += add;
        __syncthreads();
    }
    if (i < N) off[i] = buf[tid] - v;
    if (tid == 255) bsum[blockIdx.x] = buf[255];
}

__global__ void k_scan2(int* bsum, int* off) {
    __shared__ int buf[256];
    int tid = threadIdx.x;
    int v = (tid < SCAN_B) ? bsum[tid] : 0;
    buf[tid] = v;
    __syncthreads();
    for (int s = 1; s < 256; s <<= 1) {
        int add = (tid >= s) ? buf[tid - s] : 0;
        __syncthreads();
        buf[tid] += add;
        __syncthreads();
    }
    if (tid < SCAN_B) bsum[tid] = buf[tid] - v;
    if (tid == 0) off[N] = E;
}

__global__ void k_scan3(int* off, const int* __restrict__ bsum) {
    int i = blockIdx.x * 256 + threadIdx.x;
    if (i < N) off[i] += bsum[blockIdx.x];
}

// ---------- pooling indicator ----------
__global__ void k_cntg(const int* __restrict__ batch, int* cntg) {
    __shared__ int h[NG];
    if (threadIdx.x < NG) h[threadIdx.x] = 0;
    __syncthreads();
    int i = blockIdx.x * 256 + threadIdx.x;
    if (i < N) atomicAdd(&h[batch[i]], 1);
    __syncthreads();
    if (threadIdx.x < NG && h[threadIdx.x]) atomicAdd(&cntg[threadIdx.x], h[threadIdx.x]);
}

// fused: CSR fill (e<E) + U0 slice-major row init (e<N)
__global__ void k_fill(const int* __restrict__ ei, const int* __restrict__ off,
                       const int* __restrict__ pos_e, int* __restrict__ mdst,
                       const int* __restrict__ batch, const int* __restrict__ cntg,
                       const int* __restrict__ degI, uint2* Z0) {
    int e = blockIdx.x * 256 + threadIdx.x;
    if (e < E) {
        int s = ei[e];
        mdst[off[s] + pos_e[e]] = ei[E + e];
    }
    if (e < N) {
        int i = e;
        int g = batch[i];
        int c = cntg[g]; if (c < 1) c = 1;
        float v = rsqrtf((float)degI[i]) * (SCALE / (float)c);
        unsigned int byte = (unsigned int)(__builtin_amdgcn_cvt_pk_fp8_f32(v, v, 0, false) & 0xFF);
        int gq = g >> 3, gb = g & 7;             // slice, byte-in-row
        #pragma unroll
        for (int q = 0; q < 8; ++q) {
            uint2 row = make_uint2(0u, 0u);
            if (q == gq) {
                unsigned int w = byte << (8 * (gb & 3));
                if (gb < 4) row.x = w; else row.y = w;
            }
            Z0[(size_t)q * N + i] = row;
        }
    }
}

// ---------- hot kernel: one hop on one 8-graph slice ----------
// grid = 8 * NBS blocks; slice = blockIdx&7 (XCD-pinning heuristic),
// one thread per node: full edge walk, 8B gathers from a 400KB slice array.
__device__ __forceinline__ void addq8(float* acc, uint2 g) {
    float f[8];
    unp4(g.x, f); unp4(g.y, f + 4);
    #pragma unroll
    for (int k = 0; k < 8; ++k) acc[k] += f[k];
}

__global__ __launch_bounds__(256) void k_prop(
        const uint2* __restrict__ zin, uint2* __restrict__ zout,
        const int* __restrict__ off, const int* __restrict__ mdst,
        const float* __restrict__ wsq) {
    int slice = blockIdx.x & 7;
    int node  = (blockIdx.x >> 3) * 256 + threadIdx.x;
    if (node >= N) return;
    const uint2* zs = zin + (size_t)slice * N;

    float acc[8];
    {   // self term (unweighted in U-form)
        uint2 own = zs[node];
        float f[8];
        unp4(own.x, f); unp4(own.y, f + 4);
        #pragma unroll
        for (int k = 0; k < 8; ++k) acc[k] = f[k];
    }
    int e  = off[node];
    int e1 = off[node + 1];
    for (; e + 7 < e1; e += 8) {                 // 8 gathers in flight
        int d0 = mdst[e],     d1 = mdst[e + 1], d2 = mdst[e + 2], d3 = mdst[e + 3];
        int d4 = mdst[e + 4], d5 = mdst[e + 5], d6 = mdst[e + 6], d7 = mdst[e + 7];
        uint2 g0 = zs[d0], g1 = zs[d1], g2 = zs[d2], g3 = zs[d3];
        uint2 g4 = zs[d4], g5 = zs[d5], g6 = zs[d6], g7 = zs[d7];
        addq8(acc, g0); addq8(acc, g1); addq8(acc, g2); addq8(acc, g3);
        addq8(acc, g4); addq8(acc, g5); addq8(acc, g6); addq8(acc, g7);
    }
    for (; e + 3 < e1; e += 4) {
        int d0 = mdst[e], d1 = mdst[e + 1], d2 = mdst[e + 2], d3 = mdst[e + 3];
        uint2 g0 = zs[d0], g1 = zs[d1], g2 = zs[d2], g3 = zs[d3];
        addq8(acc, g0); addq8(acc, g1); addq8(acc, g2); addq8(acc, g3);
    }
    for (; e < e1; ++e) addq8(acc, zs[mdst[e]]);

    float ws = wsq[node];
    uint2 o;
    o.x = pk4(ws * acc[0], ws * acc[1], ws * acc[2], ws * acc[3]);
    o.y = pk4(ws * acc[4], ws * acc[5], ws * acc[6], ws * acc[7]);
    zout[(size_t)slice * N + node] = o;
}

// ---------- colsum: two-stage, no atomics (slice-major indexing) ----------
__global__ void k_colsum1(const unsigned int* __restrict__ Z,
                          const float* __restrict__ sdeg, float* __restrict__ part2) {
    __shared__ float red[256];
    int g = threadIdx.x & 63, sub = threadIdx.x >> 6;
    int q = g >> 3, b = g & 7;                   // slice, byte-in-row
    int wsel = (b >> 2);                         // which uint of the uint2
    int hi   = (b >> 1) & 1;
    int odd  = b & 1;
    float acc = 0.f;
    for (int i = blockIdx.x * 4 + sub; i < N; i += gridDim.x * 4) {
        unsigned int u = Z[((size_t)q * N + i) * 2 + wsel];
        floatx2 p = hi ? __builtin_amdgcn_cvt_pk_f32_fp8(u, true)
                       : __builtin_amdgcn_cvt_pk_f32_fp8(u, false);
        acc += (odd ? p.y : p.x) * sdeg[i];
    }
    red[threadIdx.x] = acc;
    __syncthreads();
    if (sub == 0)
        part2[g * CS1B + blockIdx.x] = red[g] + red[64 + g] + red[128 + g] + red[192 + g];
}

__global__ void k_colsum2(const float* __restrict__ part2, float* __restrict__ sdst) {
    __shared__ float red[256];
    int g = blockIdx.x, tid = threadIdx.x;
    float acc = 0.f;
    for (int b = tid; b < CS1B; b += 256) acc += part2[g * CS1B + b];
    red[tid] = acc;
    __syncthreads();
    for (int s = 128; s >= 1; s >>= 1) {
        if (tid < s) red[tid] += red[tid + s];
        __syncthreads();
    }
    if (tid == 0) sdst[g] = red[0] * INVSCALE;
}

// partial G = (sdeg .* U15)^T X  -- staging gathers the 8 slices per node;
// LDS row ends up g-ordered (bytes 0..63) so the inner loop is unchanged.
__global__ __launch_bounds__(256) void k_gpart(
        const uint2* __restrict__ Z, const float4* __restrict__ X,
        const float* __restrict__ sdeg, float* part) {
    __shared__ unsigned int zr[32][16];
    __shared__ float xr[32][128];
    __shared__ float sd[32];
    int tid = threadIdx.x;
    int f4 = tid & 31;
    int gs = tid >> 5;
    float4 acc[8];
    #pragma unroll
    for (int k = 0; k < 8; ++k) acc[k] = make_float4(0.f, 0.f, 0.f, 0.f);

    int per = (N + gridDim.x - 1) / gridDim.x;
    int n0 = blockIdx.x * per;
    int n1 = n0 + per; if (n1 > N) n1 = N;

    for (int nb = n0; nb < n1; nb += 32) {
        __syncthreads();
        {   // Z tile: 32 nodes x 8 slices, one uint2 per thread
            int nn = tid >> 3, q = tid & 7;
            int node = nb + nn;
            uint2 zv = make_uint2(0u, 0u);
            if (node < n1) zv = Z[(size_t)q * N + node];
            zr[nn][q * 2]     = zv.x;
            zr[nn][q * 2 + 1] = zv.y;
        }
        if (tid < 32) {
            int node = nb + tid;
            sd[tid] = (node < n1) ? sdeg[node] : 0.f;
        }
        #pragma unroll
        for (int r = 0; r < 4; ++r) {
            int l = r * 256 + tid;
            int nn = l >> 5, c4 = l & 31;
            int node = nb + nn;
            float4 xv = make_float4(0.f, 0.f, 0.f, 0.f);
            if (node < n1) xv = X[(size_t)node * 32 + c4];
            ((float4*)&xr[nn][0])[c4] = xv;
        }
        __syncthreads();
        for (int nn = 0; nn < 32; ++nn) {
            float sc = sd[nn];
            float4 xv = ((const float4*)&xr[nn][0])[f4];
            xv.x *= sc; xv.y *= sc; xv.z *= sc; xv.w *= sc;
            unsigned int za = zr[nn][gs * 2], zb = zr[nn][gs * 2 + 1];
            float zf[8];
            unp4(za, zf); unp4(zb, zf + 4);
            #pragma unroll
            for (int k = 0; k < 8; ++k) {
                acc[k].x += zf[k] * xv.x; acc[k].y += zf[k] * xv.y;
                acc[k].z += zf[k] * xv.z; acc[k].w += zf[k] * xv.w;
            }
        }
    }
    float4* dst = (float4*)(part + (size_t)blockIdx.x * 8192);
    #pragma unroll
    for (int k = 0; k < 8; ++k) dst[(gs * 8 + k) * 32 + f4] = acc[k];
}

__global__ void k_greduce(const float4* __restrict__ part, float4* G) {
    __shared__ float4 red[256];
    int tid = threadIdx.x;
    int o4 = blockIdx.x * 16 + (tid & 15);
    int slice = tid >> 4;
    float4 a = make_float4(0.f, 0.f, 0.f, 0.f);
    #pragma unroll 4
    for (int k = 0; k < GP_BLOCKS / 16; ++k) {
        float4 v = part[(size_t)(slice * (GP_BLOCKS / 16) + k) * 2048 + o4];
        a.x += v.x; a.y += v.y; a.z += v.z; a.w += v.w;
    }
    red[tid] = a;
    __syncthreads();
    for (int s = 128; s >= 16; s >>= 1) {
        if (tid < s) {
            float4 b = red[tid + s];
            red[tid].x += b.x; red[tid].y += b.y; red[tid].z += b.z; red[tid].w += b.w;
        }
        __syncthreads();
    }
    if (tid < 16) {
        float4 r = red[tid];
        G[o4] = make_float4(r.x * INVSCALE, r.y * INVSCALE, r.z * INVSCALE, r.w * INVSCALE);
    }
}

// pass1: [W1;b1] (129x160) @ W2 (160x160) -> T1c
__global__ void k_pass1(const float* __restrict__ W1, const float* __restrict__ b1,
                        const float* __restrict__ W2, float* T1c) {
    int t = blockIdx.x * 256 + threadIdx.x;
    if (t >= 129 * 160) return;
    int m = t / 160, c = t - m * 160;
    const float* arow = (m < 128) ? (W1 + m * 160) : b1;
    float a = 0.f;
    for (int k = 0; k < 160; ++k) a += arow[k] * W2[k * 160 + c];
    T1c[t] = a;
}

// pass2: [T1c; b2] (130x160) @ W3 (160x128) -> TWc
__global__ void k_pass2(const float* __restrict__ T1c, const float* __restrict__ b2,
                        const float* __restrict__ W3, float* TWc) {
    int t = blockIdx.x * 256 + threadIdx.x;
    if (t >= 130 * 128) return;
    int m = t >> 7, c = t & 127;
    const float* arow = (m < 129) ? (T1c + m * 160) : b2;
    float a = 0.f;
    for (int k = 0; k < 160; ++k) a += arow[k] * W3[k * 128 + c];
    TWc[t] = a;
}

__global__ void k_pooled(const float* __restrict__ G, const float* __restrict__ TWc,
                         const float* __restrict__ b3, const float* __restrict__ svec,
                         float* pooled) {
    int t = blockIdx.x * 256 + threadIdx.x;
    if (t >= NG * OUTC) return;
    int g = t >> 7, f = t & 127;
    float a = b3[f] + svec[64 + g] * TWc[128 * 128 + f] + svec[g] * TWc[129 * 128 + f];
    for (int k = 0; k < 128; ++k) a += G[g * 128 + k] * TWc[k * 128 + f];
    pooled[t] = a;
}

__global__ void k_head(const float* __restrict__ pooled, const float* __restrict__ fcw,
                       const float* __restrict__ fcb, float* out) {
    __shared__ float lg[ODIM];
    int g = blockIdx.x, tid = threadIdx.x;
    if (tid < ODIM) {
        float a = fcb[tid];
        for (int k = 0; k < 128; ++k) a += pooled[g * 128 + k] * fcw[k * ODIM + tid];
        lg[tid] = a;
    }
    __syncthreads();
    if (tid == 0) {
        float mx = lg[0];
        for (int j = 1; j < ODIM; ++j) mx = fmaxf(mx, lg[j]);
        float sum = 0.f;
        for (int j = 0; j < ODIM; ++j) sum += expf(lg[j] - mx);
        float lse = mx + logf(sum);
        for (int j = 0; j < ODIM; ++j) out[g * ODIM + j] = lg[j] - lse;
    }
}

extern "C" void kernel_launch(void* const* d_in, const int* in_sizes, int n_in,
                              void* d_out, int out_size, void* d_ws, size_t ws_size,
                              hipStream_t stream) {
    const float* x    = (const float*)d_in[0];
    const int*   ei   = (const int*)d_in[1];
    const int*   batch= (const int*)d_in[2];
    const float* W1   = (const float*)d_in[3];
    const float* b1   = (const float*)d_in[4];
    const float* W2   = (const float*)d_in[5];
    const float* b2   = (const float*)d_in[6];
    const float* W3   = (const float*)d_in[7];
    const float* b3   = (const float*)d_in[8];
    const float* fcw  = (const float*)d_in[9];
    const float* fcb  = (const float*)d_in[10];
    float* out = (float*)d_out;

    char* p = (char*)d_ws;
    auto alloc = [&](size_t bytes) -> void* {
        void* r = (void*)p;
        p += (bytes + 255) & ~(size_t)255;
        return r;
    };
    int*   degI    = (int*)  alloc((size_t)N * 4);
    float* wsq     = (float*)alloc((size_t)N * 4);
    float* sdeg    = (float*)alloc((size_t)N * 4);
    int*   cnt     = (int*)  alloc((size_t)N * 4);
    int*   off     = (int*)  alloc((size_t)(N + 1) * 4);
    int*   bsum    = (int*)  alloc((size_t)SCAN_B * 4);
    int*   pos_e   = (int*)  alloc((size_t)E * 4);
    int*   mdst    = (int*)  alloc((size_t)E * 4);
    int*   cntg    = (int*)  alloc((size_t)NG * 4);
    float* svec    = (float*)alloc(128 * 4);
    unsigned char* Z0 = (unsigned char*)alloc((size_t)N * 64);
    unsigned char* Z1 = (unsigned char*)alloc((size_t)N * 64);
    float* part    = (float*)alloc((size_t)GP_BLOCKS * 8192 * 4);
    float* G       = (float*)alloc(8192 * 4);
    float* T1c     = (float*)alloc(129 * 160 * 4);
    float* TWc     = (float*)alloc(130 * 128 * 4);
    float* pooled  = (float*)alloc(64 * 128 * 4);

    int nb_n = (N + 255) / 256;
    int nb_e = (E + 255) / 256;
    k_init0<<<nb_n, 256, 0, stream>>>(degI, cnt, cntg, svec);
    k_edge_count<<<nb_e, 256, 0, stream>>>(ei, degI, cnt, pos_e);
    k_scan1<<<SCAN_B, 256, 0, stream>>>(cnt, off, bsum, degI, wsq, sdeg);
    k_scan2<<<1, 256, 0, stream>>>(bsum, off);
    k_scan3<<<SCAN_B, 256, 0, stream>>>(off, bsum);
    k_cntg<<<nb_n, 256, 0, stream>>>(batch, cntg);
    k_fill<<<nb_e, 256, 0, stream>>>(ei, off, pos_e, mdst, batch, cntg, degI, (uint2*)Z0);

    unsigned char* zc = Z0;
    unsigned char* zn = Z1;
    for (int hop = 1; hop <= 15; ++hop) {
        k_prop<<<8 * NBS, 256, 0, stream>>>(
            (const uint2*)zc, (uint2*)zn, off, mdst, wsq);
        unsigned char* t = zc; zc = zn; zn = t;
        if (hop == 5) {
            k_colsum1<<<CS1B, 256, 0, stream>>>((const unsigned int*)zc, sdeg, part);
            k_colsum2<<<64, 256, 0, stream>>>(part, svec);
        }
        if (hop == 10) {
            k_colsum1<<<CS1B, 256, 0, stream>>>((const unsigned int*)zc, sdeg, part);
            k_colsum2<<<64, 256, 0, stream>>>(part, svec + 64);
        }
    }

    k_gpart<<<GP_BLOCKS, 256, 0, stream>>>((const uint2*)zc, (const float4*)x, sdeg, part);
    k_greduce<<<128, 256, 0, stream>>>((const float4*)part, (float4*)G);

    k_pass1<<<(129 * 160 + 255) / 256, 256, 0, stream>>>(W1, b1, W2, T1c);
    k_pass2<<<(130 * 128 + 255) / 256, 256, 0, stream>>>(T1c, b2, W3, TWc);
    k_pooled<<<32, 256, 0, stream>>>(G, TWc, b3, svec, pooled);
    k_head<<<NG, 64, 0, stream>>>(pooled, fcw, fcb, out);
}

// Round 12
// 502.884 us; speedup vs baseline: 1.5486x; 1.5486x over previous
//
#include <hip/hip_runtime.h>

constexpr int N    = 50000;
constexpr int E    = 800000;
constexpr int NG   = 64;
constexpr int ODIM = 10;
constexpr int OUTC = 128;
constexpr int GP_BLOCKS = 256;
constexpr int SCAN_B = (N + 255) / 256;   // 196
constexpr int CS1B   = 784;               // colsum stage-1 blocks
constexpr float SCALE    = 32768.0f;      // 2^15 for U = D^-1/2 Z (fp8 e4m3)
constexpr float INVSCALE = 1.0f / SCALE;

typedef float floatx2 __attribute__((ext_vector_type(2)));

// ---------- fp8 e4m3 helpers (r9-proven) ----------
__device__ __forceinline__ void unp4(unsigned int u, float* f) {
    floatx2 lo = __builtin_amdgcn_cvt_pk_f32_fp8(u, false);
    floatx2 hi = __builtin_amdgcn_cvt_pk_f32_fp8(u, true);
    f[0] = lo.x; f[1] = lo.y; f[2] = hi.x; f[3] = hi.y;
}
__device__ __forceinline__ unsigned int pk4(float a, float b, float c, float d) {
    int r = __builtin_amdgcn_cvt_pk_fp8_f32(a, b, 0, false);
    r = __builtin_amdgcn_cvt_pk_fp8_f32(c, d, r, true);
    return (unsigned int)r;
}

// ---------- tiny init (cntg + svec only; big arrays via memsetAsync) ----------
__global__ void k_init_small(int* cntg, float* svec) {
    int i = threadIdx.x;
    if (i < NG) cntg[i] = 0;
    if (i < 128) svec[i] = 0.f;
}

// 8 private counter copies: block b uses copy b&7 (XCD round-robin heuristic)
// -> atomic lines stay XCD-local, no cross-XCD ping-pong write-through.
__global__ void k_edge_count(const int* __restrict__ ei, int* degI8, int* cnt8,
                             int* __restrict__ pos_e) {
    int e = blockIdx.x * 256 + threadIdx.x;
    int q = blockIdx.x & 7;
    if (e < E) {
        int s = ei[e];
        int d = ei[E + e];
        atomicAdd(&degI8[q * N + d], 1);           // in-degree at dst (copy q)
        pos_e[e] = atomicAdd(&cnt8[q * N + s], 1); // out-degree + slot (copy q)
    }
}

// fused: 8-copy reduce (deg, cnt, per-copy bases) + scales + block scan
__global__ void k_scan1(const int* __restrict__ cnt8, int* __restrict__ base8,
                        int* __restrict__ off, int* bsum,
                        const int* __restrict__ degI8, float* wsq, float* sdeg) {
    __shared__ int buf[256];
    int tid = threadIdx.x;
    int i = blockIdx.x * 256 + tid;
    int total = 0;
    if (i < N) {
        int run = 0;
        #pragma unroll
        for (int q = 0; q < 8; ++q) {
            base8[q * N + i] = run;
            run += cnt8[q * N + i];
        }
        total = run;
        int deg = 1;                               // self loop
        #pragma unroll
        for (int q = 0; q < 8; ++q) deg += degI8[q * N + i];
        float d = (float)deg;
        wsq[i]  = 1.0f / d;
        sdeg[i] = sqrtf(d);
    }
    buf[tid] = total;
    __syncthreads();
    for (int s = 1; s < 256; s <<= 1) {
        int add = (tid >= s) ? buf[tid - s] : 0;
        __syncthreads();
        buf[tid] += add;
        __syncthreads();
    }
    if (i < N) off[i] = buf[tid] - total;
    if (tid == 255) bsum[blockIdx.x] = buf[255];
}

__global__ void k_scan2(int* bsum, int* off) {
    __shared__ int buf[256];
    int tid = threadIdx.x;
    int v = (tid < SCAN_B) ? bsum[tid] : 0;
    buf[tid] = v;
    __syncthreads();
    for (int s = 1; s < 256; s <<= 1) {
        int add = (tid >= s) ? buf[tid - s] : 0;
        __syncthreads();
        buf[tid] += add;
        __syncthreads();
    }
    if (tid < SCAN_B) bsum[tid] = buf[tid] - v;
    if (tid == 0) off[N] = E;
}

__global__ void k_scan3(int* off, const int* __restrict__ bsum) {
    int i = blockIdx.x * 256 + threadIdx.x;
    if (i < N) off[i] += bsum[blockIdx.x];
}

// ---------- pooling indicator ----------
__global__ void k_cntg(const int* __restrict__ batch, int* cntg) {
    __shared__ int h[NG];
    if (threadIdx.x < NG) h[threadIdx.x] = 0;
    __syncthreads();
    int i = blockIdx.x * 256 + threadIdx.x;
    if (i < N) atomicAdd(&h[batch[i]], 1);
    __syncthreads();
    if (threadIdx.x < NG && h[threadIdx.x]) atomicAdd(&cntg[threadIdx.x], h[threadIdx.x]);
}

// fused: CSR fill (e<E, slot via per-copy base) + U0 row init (e<N)
__global__ void k_fill(const int* __restrict__ ei, const int* __restrict__ off,
                       const int* __restrict__ base8, const int* __restrict__ pos_e,
                       int* __restrict__ mdst,
                       const int* __restrict__ batch, const int* __restrict__ cntg,
                       const float* __restrict__ sdeg, uint4* Z0) {
    int e = blockIdx.x * 256 + threadIdx.x;
    if (e < E) {
        int s = ei[e];
        int q = (e >> 8) & 7;                      // matches edge_count's blockIdx&7
        mdst[off[s] + base8[q * N + s] + pos_e[e]] = ei[E + e];
    }
    if (e < N) {
        int i = e;
        int g = batch[i];
        int c = cntg[g]; if (c < 1) c = 1;
        float v = (SCALE / (float)c) / sdeg[i];    // dinv = 1/sqrt(deg)
        unsigned int byte = (unsigned int)(__builtin_amdgcn_cvt_pk_fp8_f32(v, v, 0, false) & 0xFF);
        uint4 rows[4];
        #pragma unroll
        for (int q = 0; q < 4; ++q) rows[q] = make_uint4(0u, 0u, 0u, 0u);
        unsigned int* wp = (unsigned int*)rows;
        wp[g >> 2] = byte << (8 * (g & 3));
        #pragma unroll
        for (int q = 0; q < 4; ++q) Z0[(size_t)i * 4 + q] = rows[q];
    }
}

// ---------- hot kernel (r9-proven shape): U_out[s] = wsq[s]*(sum U_in[d] + U_in[s]) ----------
// N*8 threads: 4 c-lanes/node x 2 edge halves; 8 gathers in flight;
// halves combined via shfl_xor(4); no LDS, no barrier.
__device__ __forceinline__ void add16(float* acc, uint4 g) {
    float f[16];
    unp4(g.x, f); unp4(g.y, f + 4); unp4(g.z, f + 8); unp4(g.w, f + 12);
    #pragma unroll
    for (int k = 0; k < 16; ++k) acc[k] += f[k];
}

__global__ __launch_bounds__(256) void k_prop(
        const uint4* __restrict__ zin, uint2* __restrict__ zout,
        const int* __restrict__ off, const int* __restrict__ mdst,
        const float* __restrict__ wsq) {
    int t = blockIdx.x * 256 + threadIdx.x;      // N*8 threads
    int node = t >> 3;
    int sub  = (t >> 2) & 1;
    int c    = t & 3;
    if (node >= N) return;                       // no barrier below: safe

    float acc[16];
    #pragma unroll
    for (int k = 0; k < 16; ++k) acc[k] = 0.f;

    int a = off[node], b = off[node + 1];
    int half = (b - a + 1) >> 1;                 // sub0 gets ceil
    int e  = sub ? a + half : a;
    int e1 = sub ? b : a + half;
    if (!sub) {                                  // self term (unweighted in U-form)
        add16(acc, zin[(size_t)node * 4 + c]);
    }
    for (; e + 7 < e1; e += 8) {                 // 8 gathers in flight
        int d0 = mdst[e],     d1 = mdst[e + 1], d2 = mdst[e + 2], d3 = mdst[e + 3];
        int d4 = mdst[e + 4], d5 = mdst[e + 5], d6 = mdst[e + 6], d7 = mdst[e + 7];
        uint4 g0 = zin[(size_t)d0 * 4 + c];
        uint4 g1 = zin[(size_t)d1 * 4 + c];
        uint4 g2 = zin[(size_t)d2 * 4 + c];
        uint4 g3 = zin[(size_t)d3 * 4 + c];
        uint4 g4 = zin[(size_t)d4 * 4 + c];
        uint4 g5 = zin[(size_t)d5 * 4 + c];
        uint4 g6 = zin[(size_t)d6 * 4 + c];
        uint4 g7 = zin[(size_t)d7 * 4 + c];
        add16(acc, g0); add16(acc, g1); add16(acc, g2); add16(acc, g3);
        add16(acc, g4); add16(acc, g5); add16(acc, g6); add16(acc, g7);
    }
    for (; e + 3 < e1; e += 4) {
        int d0 = mdst[e], d1 = mdst[e + 1], d2 = mdst[e + 2], d3 = mdst[e + 3];
        uint4 g0 = zin[(size_t)d0 * 4 + c];
        uint4 g1 = zin[(size_t)d1 * 4 + c];
        uint4 g2 = zin[(size_t)d2 * 4 + c];
        uint4 g3 = zin[(size_t)d3 * 4 + c];
        add16(acc, g0); add16(acc, g1); add16(acc, g2); add16(acc, g3);
    }
    for (; e < e1; ++e) {
        add16(acc, zin[(size_t)mdst[e] * 4 + c]);
    }

    #pragma unroll
    for (int k = 0; k < 16; ++k) acc[k] += __shfl_xor(acc[k], 4, 64);

    float ws = wsq[node];
    uint2 o;
    if (sub == 0) {
        o.x = pk4(ws * acc[0],  ws * acc[1],  ws * acc[2],  ws * acc[3]);
        o.y = pk4(ws * acc[4],  ws * acc[5],  ws * acc[6],  ws * acc[7]);
    } else {
        o.x = pk4(ws * acc[8],  ws * acc[9],  ws * acc[10], ws * acc[11]);
        o.y = pk4(ws * acc[12], ws * acc[13], ws * acc[14], ws * acc[15]);
    }
    zout[(size_t)node * 8 + c * 2 + sub] = o;    // regular store: stays hot in caches
}

// ---------- colsum: two-stage, no atomics ----------
__global__ void k_colsum1(const unsigned int* __restrict__ Z,
                          const float* __restrict__ sdeg, float* __restrict__ part2) {
    __shared__ float red[256];
    int g = threadIdx.x & 63, sub = threadIdx.x >> 6;
    int w = g >> 2;
    int word = (g >> 1) & 1;
    int odd  = g & 1;
    float acc = 0.f;
    for (int i = blockIdx.x * 4 + sub; i < N; i += gridDim.x * 4) {
        unsigned int u = Z[(size_t)i * 16 + w];
        floatx2 p = word ? __builtin_amdgcn_cvt_pk_f32_fp8(u, true)
                         : __builtin_amdgcn_cvt_pk_f32_fp8(u, false);
        acc += (odd ? p.y : p.x) * sdeg[i];
    }
    red[threadIdx.x] = acc;
    __syncthreads();
    if (sub == 0)
        part2[g * CS1B + blockIdx.x] = red[g] + red[64 + g] + red[128 + g] + red[192 + g];
}

__global__ void k_colsum2(const float* __restrict__ part2, float* __restrict__ sdst) {
    __shared__ float red[256];
    int g = blockIdx.x, tid = threadIdx.x;
    float acc = 0.f;
    for (int b = tid; b < CS1B; b += 256) acc += part2[g * CS1B + b];
    red[tid] = acc;
    __syncthreads();
    for (int s = 128; s >= 1; s >>= 1) {
        if (tid < s) red[tid] += red[tid + s];
        __syncthreads();
    }
    if (tid == 0) sdst[g] = red[0] * INVSCALE;
}

// partial G = (sdeg .* U15)^T X
__global__ __launch_bounds__(256) void k_gpart(
        const uint4* __restrict__ Z, const float4* __restrict__ X,
        const float* __restrict__ sdeg, float* part) {
    __shared__ unsigned int zr[32][16];
    __shared__ float xr[32][128];
    __shared__ float sd[32];
    int tid = threadIdx.x;
    int f4 = tid & 31;
    int gs = tid >> 5;
    float4 acc[8];
    #pragma unroll
    for (int k = 0; k < 8; ++k) acc[k] = make_float4(0.f, 0.f, 0.f, 0.f);

    int per = (N + gridDim.x - 1) / gridDim.x;
    int n0 = blockIdx.x * per;
    int n1 = n0 + per; if (n1 > N) n1 = N;

    for (int nb = n0; nb < n1; nb += 32) {
        __syncthreads();
        if (tid < 128) {
            int nn = tid >> 2, q = tid & 3;
            int node = nb + nn;
            uint4 zv = make_uint4(0u, 0u, 0u, 0u);
            if (node < n1) zv = Z[(size_t)node * 4 + q];
            ((uint4*)&zr[nn][0])[q] = zv;
        }
        if (tid >= 192 && tid < 224) {
            int node = nb + (tid - 192);
            sd[tid - 192] = (node < n1) ? sdeg[node] : 0.f;
        }
        #pragma unroll
        for (int r = 0; r < 4; ++r) {
            int l = r * 256 + tid;
            int nn = l >> 5, c4 = l & 31;
            int node = nb + nn;
            float4 xv = make_float4(0.f, 0.f, 0.f, 0.f);
            if (node < n1) xv = X[(size_t)node * 32 + c4];
            ((float4*)&xr[nn][0])[c4] = xv;
        }
        __syncthreads();
        for (int nn = 0; nn < 32; ++nn) {
            float sc = sd[nn];
            float4 xv = ((const float4*)&xr[nn][0])[f4];
            xv.x *= sc; xv.y *= sc; xv.z *= sc; xv.w *= sc;
            unsigned int za = zr[nn][gs * 2], zb = zr[nn][gs * 2 + 1];
            float zf[8];
            unp4(za, zf); unp4(zb, zf + 4);
            #pragma unroll
            for (int k = 0; k < 8; ++k) {
                acc[k].x += zf[k] * xv.x; acc[k].y += zf[k] * xv.y;
                acc[k].z += zf[k] * xv.z; acc[k].w += zf[k] * xv.w;
            }
        }
    }
    float4* dst = (float4*)(part + (size_t)blockIdx.x * 8192);
    #pragma unroll
    for (int k = 0; k < 8; ++k) dst[(gs * 8 + k) * 32 + f4] = acc[k];
}

__global__ void k_greduce(const float4* __restrict__ part, float4* G) {
    __shared__ float4 red[256];
    int tid = threadIdx.x;
    int o4 = blockIdx.x * 16 + (tid & 15);
    int slice = tid >> 4;
    float4 a = make_float4(0.f, 0.f, 0.f, 0.f);
    #pragma unroll 4
    for (int k = 0; k < GP_BLOCKS / 16; ++k) {
        float4 v = part[(size_t)(slice * (GP_BLOCKS / 16) + k) * 2048 + o4];
        a.x += v.x; a.y += v.y; a.z += v.z; a.w += v.w;
    }
    red[tid] = a;
    __syncthreads();
    for (int s = 128; s >= 16; s >>= 1) {
        if (tid < s) {
            float4 b = red[tid + s];
            red[tid].x += b.x; red[tid].y += b.y; red[tid].z += b.z; red[tid].w += b.w;
        }
        __syncthreads();
    }
    if (tid < 16) {
        float4 r = red[tid];
        G[o4] = make_float4(r.x * INVSCALE, r.y * INVSCALE, r.z * INVSCALE, r.w * INVSCALE);
    }
}

// pass1: [W1;b1] (129x160) @ W2 (160x160) -> T1c
__global__ void k_pass1(const float* __restrict__ W1, const float* __restrict__ b1,
                        const float* __restrict__ W2, float* T1c) {
    int t = blockIdx.x * 256 + threadIdx.x;
    if (t >= 129 * 160) return;
    int m = t / 160, c = t - m * 160;
    const float* arow = (m < 128) ? (W1 + m * 160) : b1;
    float a = 0.f;
    for (int k = 0; k < 160; ++k) a += arow[k] * W2[k * 160 + c];
    T1c[t] = a;
}

// pass2: [T1c; b2] (130x160) @ W3 (160x128) -> TWc
__global__ void k_pass2(const float* __restrict__ T1c, const float* __restrict__ b2,
                        const float* __restrict__ W3, float* TWc) {
    int t = blockIdx.x * 256 + threadIdx.x;
    if (t >= 130 * 128) return;
    int m = t >> 7, c = t & 127;
    const float* arow = (m < 129) ? (T1c + m * 160) : b2;
    float a = 0.f;
    for (int k = 0; k < 160; ++k) a += arow[k] * W3[k * 128 + c];
    TWc[t] = a;
}

__global__ void k_pooled(const float* __restrict__ G, const float* __restrict__ TWc,
                         const float* __restrict__ b3, const float* __restrict__ svec,
                         float* pooled) {
    int t = blockIdx.x * 256 + threadIdx.x;
    if (t >= NG * OUTC) return;
    int g = t >> 7, f = t & 127;
    float a = b3[f] + svec[64 + g] * TWc[128 * 128 + f] + svec[g] * TWc[129 * 128 + f];
    for (int k = 0; k < 128; ++k) a += G[g * 128 + k] * TWc[k * 128 + f];
    pooled[t] = a;
}

__global__ void k_head(const float* __restrict__ pooled, const float* __restrict__ fcw,
                       const float* __restrict__ fcb, float* out) {
    __shared__ float lg[ODIM];
    int g = blockIdx.x, tid = threadIdx.x;
    if (tid < ODIM) {
        float a = fcb[tid];
        for (int k = 0; k < 128; ++k) a += pooled[g * 128 + k] * fcw[k * ODIM + tid];
        lg[tid] = a;
    }
    __syncthreads();
    if (tid == 0) {
        float mx = lg[0];
        for (int j = 1; j < ODIM; ++j) mx = fmaxf(mx, lg[j]);
        float sum = 0.f;
        for (int j = 0; j < ODIM; ++j) sum += expf(lg[j] - mx);
        float lse = mx + logf(sum);
        for (int j = 0; j < ODIM; ++j) out[g * ODIM + j] = lg[j] - lse;
    }
}

extern "C" void kernel_launch(void* const* d_in, const int* in_sizes, int n_in,
                              void* d_out, int out_size, void* d_ws, size_t ws_size,
                              hipStream_t stream) {
    const float* x    = (const float*)d_in[0];
    const int*   ei   = (const int*)d_in[1];
    const int*   batch= (const int*)d_in[2];
    const float* W1   = (const float*)d_in[3];
    const float* b1   = (const float*)d_in[4];
    const float* W2   = (const float*)d_in[5];
    const float* b2   = (const float*)d_in[6];
    const float* W3   = (const float*)d_in[7];
    const float* b3   = (const float*)d_in[8];
    const float* fcw  = (const float*)d_in[9];
    const float* fcb  = (const float*)d_in[10];
    float* out = (float*)d_out;

    char* p = (char*)d_ws;
    auto alloc = [&](size_t bytes) -> void* {
        void* r = (void*)p;
        p += (bytes + 255) & ~(size_t)255;
        return r;
    };
    int*   cnt8    = (int*)  alloc((size_t)8 * N * 4);   // adjacent: one memset
    int*   degI8   = (int*)  alloc((size_t)8 * N * 4);
    int*   base8   = (int*)  alloc((size_t)8 * N * 4);
    float* wsq     = (float*)alloc((size_t)N * 4);
    float* sdeg    = (float*)alloc((size_t)N * 4);
    int*   off     = (int*)  alloc((size_t)(N + 1) * 4);
    int*   bsum    = (int*)  alloc((size_t)SCAN_B * 4);
    int*   pos_e   = (int*)  alloc((size_t)E * 4);
    int*   mdst    = (int*)  alloc((size_t)E * 4);
    int*   cntg    = (int*)  alloc((size_t)NG * 4);
    float* svec    = (float*)alloc(128 * 4);
    unsigned char* Z0 = (unsigned char*)alloc((size_t)N * 64);
    unsigned char* Z1 = (unsigned char*)alloc((size_t)N * 64);
    float* part    = (float*)alloc((size_t)GP_BLOCKS * 8192 * 4);
    float* G       = (float*)alloc(8192 * 4);
    float* T1c     = (float*)alloc(129 * 160 * 4);
    float* TWc     = (float*)alloc(130 * 128 * 4);
    float* pooled  = (float*)alloc(64 * 128 * 4);

    int nb_n = (N + 255) / 256;
    int nb_e = (E + 255) / 256;
    (void)hipMemsetAsync(cnt8,  0, (size_t)8 * N * 4, stream);
    (void)hipMemsetAsync(degI8, 0, (size_t)8 * N * 4, stream);
    k_init_small<<<1, 256, 0, stream>>>(cntg, svec);
    k_edge_count<<<nb_e, 256, 0, stream>>>(ei, degI8, cnt8, pos_e);
    k_scan1<<<SCAN_B, 256, 0, stream>>>(cnt8, base8, off, bsum, degI8, wsq, sdeg);
    k_scan2<<<1, 256, 0, stream>>>(bsum, off);
    k_scan3<<<SCAN_B, 256, 0, stream>>>(off, bsum);
    k_cntg<<<nb_n, 256, 0, stream>>>(batch, cntg);
    k_fill<<<nb_e, 256, 0, stream>>>(ei, off, base8, pos_e, mdst, batch, cntg, sdeg, (uint4*)Z0);

    unsigned char* zc = Z0;
    unsigned char* zn = Z1;
    for (int hop = 1; hop <= 15; ++hop) {
        k_prop<<<(N * 8 + 255) / 256, 256, 0, stream>>>(
            (const uint4*)zc, (uint2*)zn, off, mdst, wsq);
        unsigned char* t = zc; zc = zn; zn = t;
        if (hop == 5) {
            k_colsum1<<<CS1B, 256, 0, stream>>>((const unsigned int*)zc, sdeg, part);
            k_colsum2<<<64, 256, 0, stream>>>(part, svec);
        }
        if (hop == 10) {
            k_colsum1<<<CS1B, 256, 0, stream>>>((const unsigned int*)zc, sdeg, part);
            k_colsum2<<<64, 256, 0, stream>>>(part, svec + 64);
        }
    }

    k_gpart<<<GP_BLOCKS, 256, 0, stream>>>((const uint4*)zc, (const float4*)x, sdeg, part);
    k_greduce<<<128, 256, 0, stream>>>((const float4*)part, (float4*)G);

    k_pass1<<<(129 * 160 + 255) / 256, 256, 0, stream>>>(W1, b1, W2, T1c);
    k_pass2<<<(130 * 128 + 255) / 256, 256, 0, stream>>>(T1c, b2, W3, TWc);
    k_pooled<<<32, 256, 0, stream>>>(G, TWc, b3, svec, pooled);
    k_head<<<NG, 64, 0, stream>>>(pooled, fcw, fcb, out);
}